// Round 20
// baseline (232.927 us; speedup 1.0000x reference)
//
#include <hip/hip_runtime.h>
#include <math.h>

typedef float fx4 __attribute__((ext_vector_type(4)));
typedef float f32x4 __attribute__((ext_vector_type(4)));
typedef float f32x16 __attribute__((ext_vector_type(16)));
typedef short bf16x8 __attribute__((ext_vector_type(8)));
typedef unsigned short us4 __attribute__((ext_vector_type(4)));
typedef unsigned short us8 __attribute__((ext_vector_type(8)));
typedef unsigned int u32x4 __attribute__((ext_vector_type(4)));

#define HDIM 1024
#define SEQ  2048
#define BATCH 2
#define NHEAD 16
#define HD    64
#define MTOT  4096
#define LSCALE 8.0f
#define LOG2E 1.44269504088896340736f

__device__ __forceinline__ unsigned short f2bf(float f) {
    union { float f; unsigned int u; } v; v.f = f;
    unsigned int r = v.u + 0x7FFFu + ((v.u >> 16) & 1u);
    return (unsigned short)(r >> 16);
}
__device__ __forceinline__ float bf2f(unsigned short h) {
    union { unsigned int u; float f; } v; v.u = ((unsigned int)h) << 16;
    return v.f;
}
// packed bf16 convert: low16 = bf16(a), high16 = bf16(b), RNE
__device__ __forceinline__ unsigned int cvt_pk_bf16(float a, float b) {
    unsigned int r;
    asm("v_cvt_pk_bf16_f32 %0, %1, %2" : "=v"(r) : "v"(a), "v"(b));
    return r;
}

// ---------------------------------------------------------------------------
// split X (fp32) -> hi/lo bf16 planes
// ---------------------------------------------------------------------------
__global__ __launch_bounds__(256)
void split_x_kernel(const float* __restrict__ X, unsigned short* __restrict__ Xh,
                    unsigned short* __restrict__ Xl, int n4)
{
    int i = blockIdx.x * 256 + threadIdx.x;
    int stride = gridDim.x * 256;
    for (; i < n4; i += stride) {
        fx4 v = *((const fx4*)X + i);
        us4 h, l;
#pragma unroll
        for (int j = 0; j < 4; ++j) {
            h[j] = f2bf(v[j]);
            l[j] = f2bf(v[j] - bf2f(h[j]));
        }
        *((us4*)Xh + i) = h;
        *((us4*)Xl + i) = l;
    }
}

// ---------------------------------------------------------------------------
// lora down: fp32 X; XA = X @ [A0|A1|A2]; out row stride 24
// ---------------------------------------------------------------------------
__global__ __launch_bounds__(64)
void lora_down_kernel(const float* __restrict__ X,
                      const float* __restrict__ A0,
                      const float* __restrict__ A1,
                      const float* __restrict__ A2,
                      float* __restrict__ out, int nmat)
{
    int row  = blockIdx.x;
    int lane = threadIdx.x;
    const float* xr = X + (size_t)row * HDIM;
    float xv[16];
#pragma unroll
    for (int i = 0; i < 16; ++i) xv[i] = xr[lane + 64 * i];
    const float* Amats[3] = {A0, A1, A2};
    for (int m = 0; m < nmat; ++m) {
        const float* A = Amats[m];
        float s[8];
#pragma unroll
        for (int c = 0; c < 8; ++c) s[c] = 0.f;
#pragma unroll
        for (int i = 0; i < 16; ++i) {
            const float* ap = A + (size_t)(lane + 64 * i) * 8;
#pragma unroll
            for (int c = 0; c < 8; ++c) s[c] += xv[i] * ap[c];
        }
#pragma unroll
        for (int c = 0; c < 8; ++c) {
#pragma unroll
            for (int off = 1; off < 64; off <<= 1)
                s[c] += __shfl_xor(s[c], off, 64);
        }
        if (lane == 0) {
#pragma unroll
            for (int c = 0; c < 8; ++c)
                out[(size_t)row * 24 + m * 8 + c] = s[c];
        }
    }
}

// ---------------------------------------------------------------------------
// transpose + split W [k][n] fp32 -> WT hi/lo bf16 [n][k]; z selects matrix.
// ---------------------------------------------------------------------------
__global__ __launch_bounds__(256)
void tsplit_w_kernel(const float* __restrict__ W0, const float* __restrict__ W1,
                     const float* __restrict__ W2, const float* __restrict__ W3,
                     unsigned short* __restrict__ WTbase)
{
    int z = blockIdx.z;
    const float* W = (z == 0) ? W0 : (z == 1) ? W1 : (z == 2) ? W2 : W3;
    unsigned short* WTh = WTbase + (size_t)z * 2097152;
    unsigned short* WTl = WTh + 1048576;
    int n0 = blockIdx.x * 64, k0 = blockIdx.y * 64;
    __shared__ unsigned int T[64][65];
    int t = threadIdx.x;
#pragma unroll
    for (int i = 0; i < 4; ++i) {
        int idx = t + 256 * i;
        int r = idx >> 4, c4 = (idx & 15) * 4;
        fx4 w = *(const fx4*)&W[(size_t)(k0 + r) * HDIM + n0 + c4];
#pragma unroll
        for (int j = 0; j < 4; ++j) {
            unsigned short hi = f2bf(w[j]);
            unsigned short lo = f2bf(w[j] - bf2f(hi));
            T[r][c4 + j] = (unsigned int)hi | ((unsigned int)lo << 16);
        }
    }
    __syncthreads();
#pragma unroll
    for (int i = 0; i < 4; ++i) {
        int idx = t + 256 * i;
        int n = idx >> 4, kg = (idx & 15) * 4;
        us4 hv, lv;
#pragma unroll
        for (int j = 0; j < 4; ++j) {
            unsigned int p = T[kg + j][n];
            hv[j] = (unsigned short)(p & 0xffffu);
            lv[j] = (unsigned short)(p >> 16);
        }
        *(us4*)&WTh[(size_t)(n0 + n) * HDIM + k0 + kg] = hv;
        *(us4*)&WTl[(size_t)(n0 + n) * HDIM + k0 + kg] = lv;
    }
}

// ---------------------------------------------------------------------------
// transpose V: vb [4096][1024] bf16 -> vt [(b*16+h)*64+d][2048] bf16
// ---------------------------------------------------------------------------
__global__ __launch_bounds__(256)
void transpose_v_kernel(const unsigned short* __restrict__ vb,
                        unsigned short* __restrict__ vt)
{
    int s0 = blockIdx.x * 64;
    int bh = blockIdx.y;               // b*16+h
    int b = bh >> 4, h = bh & 15;
    __shared__ unsigned short T[64][80];
    int t = threadIdx.x;
#pragma unroll
    for (int i = 0; i < 2; ++i) {
        int u = t + 256 * i;
        int r = u >> 3, cg = u & 7;
        us8 v = *(const us8*)&vb[(size_t)(b * SEQ + s0 + r) * HDIM + h * HD + 8 * cg];
        *(us8*)&T[r][8 * cg] = v;
    }
    __syncthreads();
#pragma unroll
    for (int i = 0; i < 2; ++i) {
        int u = t + 256 * i;
        int d = u & 63, sg = u >> 6;
        us8 v;
#pragma unroll
        for (int j = 0; j < 8; ++j) v[j] = T[8 * sg + j][d];
        *(us8*)&vt[(size_t)(bh * HD + d) * SEQ + s0 + 8 * sg] = v;
    }
}

// lora down from hi/lo bf16 planes (ctx); out stride 8
__global__ __launch_bounds__(64)
void lora_down_bf_kernel(const unsigned short* __restrict__ Xh,
                         const unsigned short* __restrict__ Xl,
                         const float* __restrict__ A,
                         float* __restrict__ out)
{
    int row  = blockIdx.x;
    int lane = threadIdx.x;
    const unsigned short* xh = Xh + (size_t)row * HDIM;
    const unsigned short* xl = Xl + (size_t)row * HDIM;
    float xv[16];
#pragma unroll
    for (int i = 0; i < 16; ++i)
        xv[i] = bf2f(xh[lane + 64 * i]) + bf2f(xl[lane + 64 * i]);
    float s[8];
#pragma unroll
    for (int c = 0; c < 8; ++c) s[c] = 0.f;
#pragma unroll
    for (int i = 0; i < 16; ++i) {
        const float* ap = A + (size_t)(lane + 64 * i) * 8;
#pragma unroll
        for (int c = 0; c < 8; ++c) s[c] += xv[i] * ap[c];
    }
#pragma unroll
    for (int c = 0; c < 8; ++c) {
#pragma unroll
        for (int off = 1; off < 64; off <<= 1)
            s[c] += __shfl_xor(s[c], off, 64);
    }
    if (lane == 0) {
#pragma unroll
        for (int c = 0; c < 8; ++c) out[(size_t)row * 8 + c] = s[c];
    }
}

// ---------------------------------------------------------------------------
// split-bf16 MFMA GEMM (32x32x16 shape): Out = X@W + LSCALE*(XA)@Bu
// BM=128: 4 waves 2x2, wave = 64x64 as 2x2 frags of 32x32 (FN=2).
// BM=64:  4 waves 1x4, wave = 64x32 as 2x1 frags (FN=1).
// A frag: row=lane&31, k=8*(lane>>5)+j.  B frag: col=lane&31, same k.
// D frag: col=lane&31, row=(reg&3)+8*(reg>>2)+4*(lane>>5)  [m74/m101].
// ZM>1: grid (8, 32*ZM); pz = y%ZM (z fastest -> X panel L2 reuse).
// ---------------------------------------------------------------------------
template<bool OUTF32, int BM, int ZM>
__global__ __launch_bounds__(256, BM == 128 ? 2 : 3)
void gemm_mfma_kernel(const unsigned short* __restrict__ Xh, const unsigned short* __restrict__ Xl,
                      const unsigned short* __restrict__ WTbase, int wsel0,
                      const float* __restrict__ XA, int xa_stride, int xa_off0,
                      const float* __restrict__ Bu0, const float* __restrict__ Bu1, const float* __restrict__ Bu2,
                      void* __restrict__ O0, void* __restrict__ O1, void* __restrict__ O2)
{
    constexpr int FN = (BM == 128) ? 2 : 1;   // 32-wide col fragments per wave
    int pz, byy;
    if (ZM > 1) { pz = blockIdx.y % ZM; byy = blockIdx.y / ZM; }
    else        { pz = blockIdx.z;      byy = blockIdx.y; }
    const unsigned short* WTh = WTbase + (size_t)(wsel0 + pz) * 2097152;
    const unsigned short* WTl = WTh + 1048576;
    const float* Bu = (pz == 0) ? Bu0 : (pz == 1) ? Bu1 : Bu2;
    void* Ovp       = (pz == 0) ? O0 : (pz == 1) ? O1 : O2;
    int xa_off = xa_off0 + pz * 8;

    int brow = byy * BM, bcol = blockIdx.x * 128;
    int t = threadIdx.x, wid = t >> 6, lane = t & 63;
    int q31 = lane & 31, g1 = lane >> 5;
    int wm = (BM == 128) ? (wid >> 1) * 64 : 0;
    int wn = (BM == 128) ? (wid & 1) * 64 : wid * 32;

    __shared__ unsigned short Ah[BM][40];
    __shared__ unsigned short Al[BM][40];
    __shared__ unsigned short Bh[128][40];
    __shared__ unsigned short Bl[128][40];

    f32x16 acc[2][FN];
#pragma unroll
    for (int i = 0; i < 2; ++i)
#pragma unroll
        for (int j = 0; j < FN; ++j)
#pragma unroll
            for (int e = 0; e < 16; ++e) acc[i][j][e] = 0.f;

    int sm = t >> 2, skg = t & 3;
    const unsigned short* aH0 = Xh  + (size_t)(brow + sm) * HDIM + 8 * skg;
    const unsigned short* aL0 = Xl  + (size_t)(brow + sm) * HDIM + 8 * skg;
    const unsigned short* bH0 = WTh + (size_t)(bcol + sm) * HDIM + 8 * skg;
    const unsigned short* bL0 = WTl + (size_t)(bcol + sm) * HDIM + 8 * skg;
    const size_t R64 = (size_t)64 * HDIM;

    us8 rAH0, rAH1, rAL0, rAL1, rBH0, rBH1, rBL0, rBL1;
    rAH0 = *(const us8*)(aH0);
    rAL0 = *(const us8*)(aL0);
    if (BM == 128) {
        rAH1 = *(const us8*)(aH0 + R64);
        rAL1 = *(const us8*)(aL0 + R64);
    }
    rBH0 = *(const us8*)(bH0);
    rBH1 = *(const us8*)(bH0 + R64);
    rBL0 = *(const us8*)(bL0);
    rBL1 = *(const us8*)(bL0 + R64);

    for (int k0 = 0; k0 < HDIM; k0 += 32) {
        __syncthreads();
        *(us8*)&Ah[sm][8 * skg] = rAH0;
        *(us8*)&Al[sm][8 * skg] = rAL0;
        if (BM == 128) {
            *(us8*)&Ah[(sm + 64) & (BM - 1)][8 * skg] = rAH1;
            *(us8*)&Al[(sm + 64) & (BM - 1)][8 * skg] = rAL1;
        }
        *(us8*)&Bh[sm][8 * skg]      = rBH0;
        *(us8*)&Bh[sm + 64][8 * skg] = rBH1;
        *(us8*)&Bl[sm][8 * skg]      = rBL0;
        *(us8*)&Bl[sm + 64][8 * skg] = rBL1;
        __syncthreads();
        if (k0 + 32 < HDIM) {
            int ko = k0 + 32;
            rAH0 = *(const us8*)(aH0 + ko);
            rAL0 = *(const us8*)(aL0 + ko);
            if (BM == 128) {
                rAH1 = *(const us8*)(aH0 + R64 + ko);
                rAL1 = *(const us8*)(aL0 + R64 + ko);
            }
            rBH0 = *(const us8*)(bH0 + ko);
            rBH1 = *(const us8*)(bH0 + R64 + ko);
            rBL0 = *(const us8*)(bL0 + ko);
            rBL1 = *(const us8*)(bL0 + R64 + ko);
        }
        bf16x8 fah[2][2], fal[2][2], fbh[FN][2], fbl[FN][2];
#pragma unroll
        for (int fm = 0; fm < 2; ++fm)
#pragma unroll
            for (int kc = 0; kc < 2; ++kc) {
                fah[fm][kc] = *(const bf16x8*)&Ah[wm + 32 * fm + q31][16 * kc + 8 * g1];
                fal[fm][kc] = *(const bf16x8*)&Al[wm + 32 * fm + q31][16 * kc + 8 * g1];
            }
#pragma unroll
        for (int fn = 0; fn < FN; ++fn)
#pragma unroll
            for (int kc = 0; kc < 2; ++kc) {
                fbh[fn][kc] = *(const bf16x8*)&Bh[wn + 32 * fn + q31][16 * kc + 8 * g1];
                fbl[fn][kc] = *(const bf16x8*)&Bl[wn + 32 * fn + q31][16 * kc + 8 * g1];
            }
#pragma unroll
        for (int fm = 0; fm < 2; ++fm)
#pragma unroll
            for (int fn = 0; fn < FN; ++fn) {
                f32x16 a = acc[fm][fn];
#pragma unroll
                for (int kc = 0; kc < 2; ++kc) {
                    a = __builtin_amdgcn_mfma_f32_32x32x16_bf16(fah[fm][kc], fbh[fn][kc], a, 0, 0, 0);
                    a = __builtin_amdgcn_mfma_f32_32x32x16_bf16(fah[fm][kc], fbl[fn][kc], a, 0, 0, 0);
                    a = __builtin_amdgcn_mfma_f32_32x32x16_bf16(fal[fm][kc], fbh[fn][kc], a, 0, 0, 0);
                }
                acc[fm][fn] = a;
            }
    }

    // LoRA epilogue + store: acc[fm][fn][reg], row = wm+32fm+(reg&3)+8(reg>>2)+4g1
    float lb[8][FN];
#pragma unroll
    for (int rr = 0; rr < 8; ++rr)
#pragma unroll
        for (int fn = 0; fn < FN; ++fn)
            lb[rr][fn] = Bu[(size_t)rr * HDIM + bcol + wn + 32 * fn + q31] * LSCALE;

#pragma unroll
    for (int fm = 0; fm < 2; ++fm)
#pragma unroll
        for (int blk = 0; blk < 4; ++blk) {
            int rowbase = brow + wm + 32 * fm + 8 * blk + 4 * g1;
            float la[4][8];
#pragma unroll
            for (int r = 0; r < 4; ++r) {
                const float* lap = XA + (size_t)(rowbase + r) * xa_stride + xa_off;
                fx4 q0 = *(const fx4*)lap;
                fx4 q1 = *(const fx4*)(lap + 4);
#pragma unroll
                for (int j = 0; j < 4; ++j) { la[r][j] = q0[j]; la[r][4 + j] = q1[j]; }
            }
#pragma unroll
            for (int fn = 0; fn < FN; ++fn)
#pragma unroll
                for (int r = 0; r < 4; ++r) {
                    float sum = acc[fm][fn][4 * blk + r];
#pragma unroll
                    for (int rr = 0; rr < 8; ++rr) sum += la[r][rr] * lb[rr][fn];
                    size_t row = (size_t)(rowbase + r);
                    int col = bcol + wn + 32 * fn + q31;
                    if (OUTF32) ((float*)Ovp)[row * HDIM + col] = sum;
                    else ((unsigned short*)Ovp)[row * HDIM + col] = f2bf(sum);
                }
        }
}

// ---------------------------------------------------------------------------
// flash attention, 32x32x16 MFMA, swapped operands, fixed-max softmax.
// ---------------------------------------------------------------------------
#define QBLK 128
#define KVB  64
#define NT   (SEQ / KVB)

__global__ __launch_bounds__(256, 2)
void attn_mfma_kernel(const unsigned short* __restrict__ Qg, const unsigned short* __restrict__ Kg,
                      const unsigned short* __restrict__ Vt, const float* __restrict__ mask,
                      unsigned short* __restrict__ Ch, unsigned short* __restrict__ Cl)
{
    int qt = blockIdx.x, hd = blockIdx.y, b = blockIdx.z;
    int t    = threadIdx.x;
    int wid  = t >> 6;
    int lane = t & 63;
    int q31  = lane & 31;
    int g1   = lane >> 5;

    __shared__ __align__(16) unsigned short Ks[2][64][72];
    __shared__ __align__(16) unsigned short Vs[2][64][72];   // Vs[d][s]
    __shared__ __align__(16) float Msd[2][64];

    bf16x8 qB[4];
    const unsigned short* qp = Qg + (size_t)(b * SEQ + qt * QBLK + wid * 32 + q31) * HDIM + hd * HD;
#pragma unroll
    for (int kc = 0; kc < 4; ++kc)
        qB[kc] = *(const bf16x8*)(qp + 16 * kc + 8 * g1);

    float m0 = 0.f;
    f32x4 l4 = (f32x4){0.f, 0.f, 0.f, 0.f};
    f32x16 accO[2];
#pragma unroll
    for (int dh = 0; dh < 2; ++dh)
#pragma unroll
        for (int i = 0; i < 16; ++i) accO[dh][i] = 0.f;

    const unsigned short* kp0 = Kg + (size_t)(b * SEQ) * HDIM + hd * HD;
    const unsigned short* vt0 = Vt + (size_t)((b * NHEAD + hd) * HD) * SEQ;

    const float QSCL = 0.125f * LOG2E;
    const float MSCL = -10000.0f * LOG2E;

    int r0 = t >> 3,           c0 = (t & 7) * 8;
    int r1 = (t + 256) >> 3,   c1 = c0;

    *(us8*)&Ks[0][r0][c0] = *(const us8*)(kp0 + (size_t)r0 * HDIM + c0);
    *(us8*)&Ks[0][r1][c1] = *(const us8*)(kp0 + (size_t)r1 * HDIM + c1);
    *(us8*)&Vs[0][r0][c0] = *(const us8*)(vt0 + (size_t)r0 * SEQ + c0);
    *(us8*)&Vs[0][r1][c1] = *(const us8*)(vt0 + (size_t)r1 * SEQ + c1);
    if (t < 64) Msd[0][t] = (1.0f - mask[b * SEQ + t]) * MSCL;
    __syncthreads();

    int cur = 0;
    for (int kt = 0; kt < NT; ++kt) {
        us8 knr0, knr1, vnr0, vnr1;
        float mreg = 1.0f;
        bool more = (kt + 1 < NT);
        if (more) {
            const unsigned short* kp = kp0 + (size_t)(kt + 1) * KVB * HDIM;
            const unsigned short* vp = vt0 + (kt + 1) * KVB;
            knr0 = *(const us8*)(kp + (size_t)r0 * HDIM + c0);
            knr1 = *(const us8*)(kp + (size_t)r1 * HDIM + c1);
            vnr0 = *(const us8*)(vp + (size_t)r0 * SEQ + c0);
            vnr1 = *(const us8*)(vp + (size_t)r1 * SEQ + c1);
            if (t < 64) mreg = mask[b * SEQ + (kt + 1) * KVB + t];
        }

        f32x16 sQ[2];
#pragma unroll
        for (int kvh = 0; kvh < 2; ++kvh) {
            f32x16 a;
#pragma unroll
            for (int i = 0; i < 16; ++i) a[i] = 0.f;
#pragma unroll
            for (int kc = 0; kc < 4; ++kc) {
                bf16x8 kA = *(const bf16x8*)&Ks[cur][32 * kvh + q31][16 * kc + 8 * g1];
                a = __builtin_amdgcn_mfma_f32_32x32x16_bf16(kA, qB[kc], a, 0, 0, 0);
            }
            sQ[kvh] = a;
        }

#pragma unroll
        for (int kvh = 0; kvh < 2; ++kvh)
#pragma unroll
            for (int hh = 0; hh < 4; ++hh) {
                fx4 msk = *(const fx4*)&Msd[cur][32 * kvh + 8 * hh + 4 * g1];
#pragma unroll
                for (int r = 0; r < 4; ++r)
                    sQ[kvh][4 * hh + r] = fmaf(sQ[kvh][4 * hh + r], QSCL, msk[r]);
            }

        if (kt == 0) {
            float mx = sQ[0][0];
#pragma unroll
            for (int kvh = 0; kvh < 2; ++kvh)
#pragma unroll
                for (int i = 0; i < 16; ++i) mx = fmaxf(mx, sQ[kvh][i]);
            mx = fmaxf(mx, __shfl_xor(mx, 32, 64));
            m0 = fmaxf(mx, -64.f);
        }

#pragma unroll
        for (int kvh = 0; kvh < 2; ++kvh)
#pragma unroll
            for (int hh = 0; hh < 4; ++hh)
#pragma unroll
                for (int r = 0; r < 4; ++r) {
                    float p = exp2f(sQ[kvh][4 * hh + r] - m0);
                    sQ[kvh][4 * hh + r] = p;
                    l4[r] += p;
                }

        unsigned int pkx[2][4], pky[2][4];
#pragma unroll
        for (int kvh = 0; kvh < 2; ++kvh)
#pragma unroll
            for (int hh = 0; hh < 4; ++hh) {
                pkx[kvh][hh] = cvt_pk_bf16(sQ[kvh][4 * hh + 0], sQ[kvh][4 * hh + 1]);
                pky[kvh][hh] = cvt_pk_bf16(sQ[kvh][4 * hh + 2], sQ[kvh][4 * hh + 3]);
            }

        bf16x8 pB[4];
#pragma unroll
        for (int kvh = 0; kvh < 2; ++kvh)
#pragma unroll
            for (int kc2 = 0; kc2 < 2; ++kc2) {
                unsigned int x0 = pkx[kvh][2 * kc2], x1 = pkx[kvh][2 * kc2 + 1];
                unsigned int y0 = pky[kvh][2 * kc2], y1 = pky[kvh][2 * kc2 + 1];
                asm("v_permlane32_swap_b32 %0, %1" : "+v"(x0), "+v"(x1));
                asm("v_permlane32_swap_b32 %0, %1" : "+v"(y0), "+v"(y1));
                u32x4 dd;
                dd[0] = x0; dd[1] = y0; dd[2] = x1; dd[3] = y1;
                pB[2 * kvh + kc2] = *(bf16x8*)&dd;
            }

#pragma unroll
        for (int dh = 0; dh < 2; ++dh) {
            f32x16 a = accO[dh];
#pragma unroll
            for (int kcp = 0; kcp < 4; ++kcp) {
                bf16x8 vA = *(const bf16x8*)&Vs[cur][32 * dh + q31][16 * kcp + 8 * g1];
                a = __builtin_amdgcn_mfma_f32_32x32x16_bf16(vA, pB[kcp], a, 0, 0, 0);
            }
            accO[dh] = a;
        }

        if (more) {
            *(us8*)&Ks[cur ^ 1][r0][c0] = knr0;
            *(us8*)&Ks[cur ^ 1][r1][c1] = knr1;
            *(us8*)&Vs[cur ^ 1][r0][c0] = vnr0;
            *(us8*)&Vs[cur ^ 1][r1][c1] = vnr1;
            if (t < 64) Msd[cur ^ 1][t] = (1.0f - mreg) * MSCL;
        }
        __syncthreads();
        cur ^= 1;
    }

    float l = (l4[0] + l4[1]) + (l4[2] + l4[3]);
    l += __shfl_xor(l, 32, 64);
    float inv = 1.0f / l;
    size_t row = (size_t)(b * SEQ + qt * QBLK + wid * 32 + q31);
#pragma unroll
    for (int dh = 0; dh < 2; ++dh)
#pragma unroll
        for (int hh = 0; hh < 4; ++hh) {
            us4 hv, lv;
#pragma unroll
            for (int r = 0; r < 4; ++r) {
                float o = accO[dh][4 * hh + r] * inv;
                unsigned short hi = f2bf(o);
                hv[r] = hi;
                lv[r] = f2bf(o - bf2f(hi));
            }
            size_t idx = row * HDIM + hd * HD + 32 * dh + 8 * hh + 4 * g1;
            *(us4*)&Ch[idx] = hv;
            *(us4*)&Cl[idx] = lv;
        }
}

// ---------------------------------------------------------------------------
extern "C" void kernel_launch(void* const* d_in, const int* in_sizes, int n_in,
                              void* d_out, int out_size, void* d_ws, size_t ws_size,
                              hipStream_t stream)
{
    const float* hs   = (const float*)d_in[0];
    const float* mask = (const float*)d_in[1];
    const float* Wq = (const float*)d_in[2];
    const float* Wk = (const float*)d_in[3];
    const float* Wv = (const float*)d_in[4];
    const float* Wo = (const float*)d_in[5];
    const float* Aq = (const float*)d_in[6];
    const float* Bq = (const float*)d_in[7];
    const float* Ak = (const float*)d_in[8];
    const float* Bk = (const float*)d_in[9];
    const float* Av = (const float*)d_in[10];
    const float* Bv = (const float*)d_in[11];
    const float* Ao = (const float*)d_in[12];
    const float* Bo = (const float*)d_in[13];
    float* out = (float*)d_out;

    char* w = (char*)d_ws;
    unsigned short* Xh = (unsigned short*)(w);                       // 8 MB (later Ch)
    unsigned short* Xl = (unsigned short*)(w + ((size_t)8 << 20));   // 8 MB (later Cl)
    unsigned short* WT = (unsigned short*)(w + ((size_t)16 << 20));  // 16 MB (8 planes)
    unsigned short* qb = (unsigned short*)(w + ((size_t)32 << 20));  // 8 MB
    unsigned short* kb = (unsigned short*)(w + ((size_t)40 << 20));  // 8 MB
    unsigned short* vb = (unsigned short*)(w + ((size_t)48 << 20));  // 8 MB
    unsigned short* vt = (unsigned short*)(w + ((size_t)56 << 20));  // 8 MB
    float* hsA  = (float*)(w + ((size_t)64 << 20));                  // 4096*24*4
    float* ctxA = (float*)(w + ((size_t)64 << 20) + 400 * 1024);     // 4096*8*4

    split_x_kernel<<<2048, 256, 0, stream>>>(hs, Xh, Xl, MTOT * HDIM / 4);
    tsplit_w_kernel<<<dim3(16, 16, 4), 256, 0, stream>>>(Wq, Wk, Wv, Wo, WT);
    lora_down_kernel<<<MTOT, 64, 0, stream>>>(hs, Aq, Ak, Av, hsA, 3);
    gemm_mfma_kernel<false, 128, 3><<<dim3(8, 96), 256, 0, stream>>>(
        Xh, Xl, WT, 0, hsA, 24, 0, Bq, Bk, Bv, qb, kb, vb);
    transpose_v_kernel<<<dim3(SEQ / 64, BATCH * NHEAD), 256, 0, stream>>>(vb, vt);
    attn_mfma_kernel<<<dim3(SEQ / QBLK, NHEAD, BATCH), 256, 0, stream>>>(
        qb, kb, vt, mask, Xh /*Ch*/, Xl /*Cl*/);
    lora_down_bf_kernel<<<MTOT, 64, 0, stream>>>(Xh, Xl, Ao, ctxA);
    gemm_mfma_kernel<true, 64, 1><<<dim3(8, 64, 1), 256, 0, stream>>>(
        Xh, Xl, WT, 3, ctxA, 8, 0, Bo, Bo, Bo, out, out, out);
}

// Round 21
// 196.438 us; speedup vs baseline: 1.1858x; 1.1858x over previous
//
#include <hip/hip_runtime.h>
#include <math.h>

typedef float fx4 __attribute__((ext_vector_type(4)));
typedef float f32x4 __attribute__((ext_vector_type(4)));
typedef float f32x16 __attribute__((ext_vector_type(16)));
typedef short bf16x8 __attribute__((ext_vector_type(8)));
typedef unsigned short us4 __attribute__((ext_vector_type(4)));
typedef unsigned short us8 __attribute__((ext_vector_type(8)));
typedef unsigned int u32x4 __attribute__((ext_vector_type(4)));

#define HDIM 1024
#define SEQ  2048
#define BATCH 2
#define NHEAD 16
#define HD    64
#define MTOT  4096
#define LSCALE 8.0f
#define LOG2E 1.44269504088896340736f

__device__ __forceinline__ unsigned short f2bf(float f) {
    union { float f; unsigned int u; } v; v.f = f;
    unsigned int r = v.u + 0x7FFFu + ((v.u >> 16) & 1u);
    return (unsigned short)(r >> 16);
}
__device__ __forceinline__ float bf2f(unsigned short h) {
    union { unsigned int u; float f; } v; v.u = ((unsigned int)h) << 16;
    return v.f;
}
// packed bf16 convert: low16 = bf16(a), high16 = bf16(b), RNE
__device__ __forceinline__ unsigned int cvt_pk_bf16(float a, float b) {
    unsigned int r;
    asm("v_cvt_pk_bf16_f32 %0, %1, %2" : "=v"(r) : "v"(a), "v"(b));
    return r;
}

// ---------------------------------------------------------------------------
// split X (fp32) -> hi/lo bf16 planes
// ---------------------------------------------------------------------------
__global__ __launch_bounds__(256)
void split_x_kernel(const float* __restrict__ X, unsigned short* __restrict__ Xh,
                    unsigned short* __restrict__ Xl, int n4)
{
    int i = blockIdx.x * 256 + threadIdx.x;
    int stride = gridDim.x * 256;
    for (; i < n4; i += stride) {
        fx4 v = *((const fx4*)X + i);
        us4 h, l;
#pragma unroll
        for (int j = 0; j < 4; ++j) {
            h[j] = f2bf(v[j]);
            l[j] = f2bf(v[j] - bf2f(h[j]));
        }
        *((us4*)Xh + i) = h;
        *((us4*)Xl + i) = l;
    }
}

// ---------------------------------------------------------------------------
// lora down: fp32 X; XA = X @ [A0|A1|A2]; out row stride 24
// ---------------------------------------------------------------------------
__global__ __launch_bounds__(64)
void lora_down_kernel(const float* __restrict__ X,
                      const float* __restrict__ A0,
                      const float* __restrict__ A1,
                      const float* __restrict__ A2,
                      float* __restrict__ out, int nmat)
{
    int row  = blockIdx.x;
    int lane = threadIdx.x;
    const float* xr = X + (size_t)row * HDIM;
    float xv[16];
#pragma unroll
    for (int i = 0; i < 16; ++i) xv[i] = xr[lane + 64 * i];
    const float* Amats[3] = {A0, A1, A2};
    for (int m = 0; m < nmat; ++m) {
        const float* A = Amats[m];
        float s[8];
#pragma unroll
        for (int c = 0; c < 8; ++c) s[c] = 0.f;
#pragma unroll
        for (int i = 0; i < 16; ++i) {
            const float* ap = A + (size_t)(lane + 64 * i) * 8;
#pragma unroll
            for (int c = 0; c < 8; ++c) s[c] += xv[i] * ap[c];
        }
#pragma unroll
        for (int c = 0; c < 8; ++c) {
#pragma unroll
            for (int off = 1; off < 64; off <<= 1)
                s[c] += __shfl_xor(s[c], off, 64);
        }
        if (lane == 0) {
#pragma unroll
            for (int c = 0; c < 8; ++c)
                out[(size_t)row * 24 + m * 8 + c] = s[c];
        }
    }
}

// ---------------------------------------------------------------------------
// transpose + split W [k][n] fp32 -> WT hi/lo bf16 [n][k]; z selects matrix.
// ---------------------------------------------------------------------------
__global__ __launch_bounds__(256)
void tsplit_w_kernel(const float* __restrict__ W0, const float* __restrict__ W1,
                     const float* __restrict__ W2, const float* __restrict__ W3,
                     unsigned short* __restrict__ WTbase)
{
    int z = blockIdx.z;
    const float* W = (z == 0) ? W0 : (z == 1) ? W1 : (z == 2) ? W2 : W3;
    unsigned short* WTh = WTbase + (size_t)z * 2097152;
    unsigned short* WTl = WTh + 1048576;
    int n0 = blockIdx.x * 64, k0 = blockIdx.y * 64;
    __shared__ unsigned int T[64][65];
    int t = threadIdx.x;
#pragma unroll
    for (int i = 0; i < 4; ++i) {
        int idx = t + 256 * i;
        int r = idx >> 4, c4 = (idx & 15) * 4;
        fx4 w = *(const fx4*)&W[(size_t)(k0 + r) * HDIM + n0 + c4];
#pragma unroll
        for (int j = 0; j < 4; ++j) {
            unsigned short hi = f2bf(w[j]);
            unsigned short lo = f2bf(w[j] - bf2f(hi));
            T[r][c4 + j] = (unsigned int)hi | ((unsigned int)lo << 16);
        }
    }
    __syncthreads();
#pragma unroll
    for (int i = 0; i < 4; ++i) {
        int idx = t + 256 * i;
        int n = idx >> 4, kg = (idx & 15) * 4;
        us4 hv, lv;
#pragma unroll
        for (int j = 0; j < 4; ++j) {
            unsigned int p = T[kg + j][n];
            hv[j] = (unsigned short)(p & 0xffffu);
            lv[j] = (unsigned short)(p >> 16);
        }
        *(us4*)&WTh[(size_t)(n0 + n) * HDIM + k0 + kg] = hv;
        *(us4*)&WTl[(size_t)(n0 + n) * HDIM + k0 + kg] = lv;
    }
}

// ---------------------------------------------------------------------------
// transpose V: vb [4096][1024] bf16 -> vt [(b*16+h)*64+d][2048] bf16
// ---------------------------------------------------------------------------
__global__ __launch_bounds__(256)
void transpose_v_kernel(const unsigned short* __restrict__ vb,
                        unsigned short* __restrict__ vt)
{
    int s0 = blockIdx.x * 64;
    int bh = blockIdx.y;               // b*16+h
    int b = bh >> 4, h = bh & 15;
    __shared__ unsigned short T[64][80];
    int t = threadIdx.x;
#pragma unroll
    for (int i = 0; i < 2; ++i) {
        int u = t + 256 * i;
        int r = u >> 3, cg = u & 7;
        us8 v = *(const us8*)&vb[(size_t)(b * SEQ + s0 + r) * HDIM + h * HD + 8 * cg];
        *(us8*)&T[r][8 * cg] = v;
    }
    __syncthreads();
#pragma unroll
    for (int i = 0; i < 2; ++i) {
        int u = t + 256 * i;
        int d = u & 63, sg = u >> 6;
        us8 v;
#pragma unroll
        for (int j = 0; j < 8; ++j) v[j] = T[8 * sg + j][d];
        *(us8*)&vt[(size_t)(bh * HD + d) * SEQ + s0 + 8 * sg] = v;
    }
}

// lora down from hi/lo bf16 planes (ctx); out stride 8
__global__ __launch_bounds__(64)
void lora_down_bf_kernel(const unsigned short* __restrict__ Xh,
                         const unsigned short* __restrict__ Xl,
                         const float* __restrict__ A,
                         float* __restrict__ out)
{
    int row  = blockIdx.x;
    int lane = threadIdx.x;
    const unsigned short* xh = Xh + (size_t)row * HDIM;
    const unsigned short* xl = Xl + (size_t)row * HDIM;
    float xv[16];
#pragma unroll
    for (int i = 0; i < 16; ++i)
        xv[i] = bf2f(xh[lane + 64 * i]) + bf2f(xl[lane + 64 * i]);
    float s[8];
#pragma unroll
    for (int c = 0; c < 8; ++c) s[c] = 0.f;
#pragma unroll
    for (int i = 0; i < 16; ++i) {
        const float* ap = A + (size_t)(lane + 64 * i) * 8;
#pragma unroll
        for (int c = 0; c < 8; ++c) s[c] += xv[i] * ap[c];
    }
#pragma unroll
    for (int c = 0; c < 8; ++c) {
#pragma unroll
        for (int off = 1; off < 64; off <<= 1)
            s[c] += __shfl_xor(s[c], off, 64);
    }
    if (lane == 0) {
#pragma unroll
        for (int c = 0; c < 8; ++c) out[(size_t)row * 8 + c] = s[c];
    }
}

// ---------------------------------------------------------------------------
// 2-term split-bf16 MFMA GEMM: Out ~= bf16(X)@W + LSCALE*(XA)@Bu
//   X@W approximated as Xh@(Wh + Wl): the x-lo term dropped (2 MFMAs/frag).
// BM=128: 4 waves 2x2 of 64x64 (FN=4).  BM=64: 4 waves 1x4 of 64x32 (FN=2).
// ZM>1: grid (8, 32*ZM); pz = y%ZM (z fastest -> X panel L2 reuse).
// ---------------------------------------------------------------------------
template<bool OUTF32, int BM, int ZM>
__global__ __launch_bounds__(256, BM == 128 ? 2 : 3)
void gemm_mfma_kernel(const unsigned short* __restrict__ Xh,
                      const unsigned short* __restrict__ WTbase, int wsel0,
                      const float* __restrict__ XA, int xa_stride, int xa_off0,
                      const float* __restrict__ Bu0, const float* __restrict__ Bu1, const float* __restrict__ Bu2,
                      void* __restrict__ O0, void* __restrict__ O1, void* __restrict__ O2)
{
    constexpr int FN = (BM == 128) ? 4 : 2;
    int pz, byy;
    if (ZM > 1) { pz = blockIdx.y % ZM; byy = blockIdx.y / ZM; }
    else        { pz = blockIdx.z;      byy = blockIdx.y; }
    const unsigned short* WTh = WTbase + (size_t)(wsel0 + pz) * 2097152;
    const unsigned short* WTl = WTh + 1048576;
    const float* Bu = (pz == 0) ? Bu0 : (pz == 1) ? Bu1 : Bu2;
    void* Ovp       = (pz == 0) ? O0 : (pz == 1) ? O1 : O2;
    int xa_off = xa_off0 + pz * 8;

    int brow = byy * BM, bcol = blockIdx.x * 128;
    int t = threadIdx.x, wid = t >> 6, lane = t & 63, l15 = lane & 15, g = lane >> 4;
    int wm = (BM == 128) ? (wid >> 1) * 64 : 0;
    int wn = (BM == 128) ? (wid & 1) * 64 : wid * 32;

    __shared__ unsigned short Ah[BM][40];
    __shared__ unsigned short Bh[128][40];
    __shared__ unsigned short Bl[128][40];

    f32x4 acc[4][FN];
#pragma unroll
    for (int i = 0; i < 4; ++i)
#pragma unroll
        for (int j = 0; j < FN; ++j) acc[i][j] = (f32x4){0.f, 0.f, 0.f, 0.f};

    int sm = t >> 2, skg = t & 3;
    const unsigned short* aH0 = Xh  + (size_t)(brow + sm) * HDIM + 8 * skg;
    const unsigned short* bH0 = WTh + (size_t)(bcol + sm) * HDIM + 8 * skg;
    const unsigned short* bL0 = WTl + (size_t)(bcol + sm) * HDIM + 8 * skg;
    const size_t R64 = (size_t)64 * HDIM;

    us8 rAH0, rAH1, rBH0, rBH1, rBL0, rBL1;
    rAH0 = *(const us8*)(aH0);
    if (BM == 128) rAH1 = *(const us8*)(aH0 + R64);
    rBH0 = *(const us8*)(bH0);
    rBH1 = *(const us8*)(bH0 + R64);
    rBL0 = *(const us8*)(bL0);
    rBL1 = *(const us8*)(bL0 + R64);

    for (int k0 = 0; k0 < HDIM; k0 += 32) {
        __syncthreads();
        *(us8*)&Ah[sm][8 * skg] = rAH0;
        if (BM == 128)
            *(us8*)&Ah[(sm + 64) & (BM - 1)][8 * skg] = rAH1;
        *(us8*)&Bh[sm][8 * skg]      = rBH0;
        *(us8*)&Bh[sm + 64][8 * skg] = rBH1;
        *(us8*)&Bl[sm][8 * skg]      = rBL0;
        *(us8*)&Bl[sm + 64][8 * skg] = rBL1;
        __syncthreads();
        if (k0 + 32 < HDIM) {
            int ko = k0 + 32;
            rAH0 = *(const us8*)(aH0 + ko);
            if (BM == 128) rAH1 = *(const us8*)(aH0 + R64 + ko);
            rBH0 = *(const us8*)(bH0 + ko);
            rBH1 = *(const us8*)(bH0 + R64 + ko);
            rBL0 = *(const us8*)(bL0 + ko);
            rBL1 = *(const us8*)(bL0 + R64 + ko);
        }
        bf16x8 fah[4], fbh[FN], fbl[FN];
#pragma unroll
        for (int f = 0; f < 4; ++f)
            fah[f] = *(const bf16x8*)&Ah[wm + 16 * f + l15][8 * g];
#pragma unroll
        for (int f = 0; f < FN; ++f) {
            fbh[f] = *(const bf16x8*)&Bh[wn + 16 * f + l15][8 * g];
            fbl[f] = *(const bf16x8*)&Bl[wn + 16 * f + l15][8 * g];
        }
#pragma unroll
        for (int fm = 0; fm < 4; ++fm)
#pragma unroll
            for (int fn = 0; fn < FN; ++fn) {
                f32x4 a = acc[fm][fn];
                a = __builtin_amdgcn_mfma_f32_16x16x32_bf16(fah[fm], fbh[fn], a, 0, 0, 0);
                a = __builtin_amdgcn_mfma_f32_16x16x32_bf16(fah[fm], fbl[fn], a, 0, 0, 0);
                acc[fm][fn] = a;
            }
    }

    // LoRA epilogue + store
    float lb[8][FN];
#pragma unroll
    for (int rr = 0; rr < 8; ++rr)
#pragma unroll
        for (int fn = 0; fn < FN; ++fn)
            lb[rr][fn] = Bu[(size_t)rr * HDIM + bcol + wn + 16 * fn + l15] * LSCALE;

#pragma unroll
    for (int fm = 0; fm < 4; ++fm) {
        float la[4][8];
#pragma unroll
        for (int r = 0; r < 4; ++r) {
            int row = brow + wm + 16 * fm + 4 * g + r;
            const float* lap = XA + (size_t)row * xa_stride + xa_off;
            fx4 q0 = *(const fx4*)lap;
            fx4 q1 = *(const fx4*)(lap + 4);
#pragma unroll
            for (int j = 0; j < 4; ++j) { la[r][j] = q0[j]; la[r][4 + j] = q1[j]; }
        }
#pragma unroll
        for (int fn = 0; fn < FN; ++fn)
#pragma unroll
            for (int r = 0; r < 4; ++r) {
                float sum = acc[fm][fn][r];
#pragma unroll
                for (int rr = 0; rr < 8; ++rr) sum += la[r][rr] * lb[rr][fn];
                size_t row = (size_t)(brow + wm + 16 * fm + 4 * g + r);
                int col = bcol + wn + 16 * fn + l15;
                if (OUTF32) ((float*)Ovp)[row * HDIM + col] = sum;
                else ((unsigned short*)Ovp)[row * HDIM + col] = f2bf(sum);
            }
    }
}

// ---------------------------------------------------------------------------
// flash attention, 32x32x16 MFMA, swapped operands, fixed-max softmax.
// ---------------------------------------------------------------------------
#define QBLK 128
#define KVB  64
#define NT   (SEQ / KVB)

__global__ __launch_bounds__(256, 2)
void attn_mfma_kernel(const unsigned short* __restrict__ Qg, const unsigned short* __restrict__ Kg,
                      const unsigned short* __restrict__ Vt, const float* __restrict__ mask,
                      unsigned short* __restrict__ Ch, unsigned short* __restrict__ Cl)
{
    int qt = blockIdx.x, hd = blockIdx.y, b = blockIdx.z;
    int t    = threadIdx.x;
    int wid  = t >> 6;
    int lane = t & 63;
    int q31  = lane & 31;
    int g1   = lane >> 5;

    __shared__ __align__(16) unsigned short Ks[2][64][72];
    __shared__ __align__(16) unsigned short Vs[2][64][72];   // Vs[d][s]
    __shared__ __align__(16) float Msd[2][64];

    bf16x8 qB[4];
    const unsigned short* qp = Qg + (size_t)(b * SEQ + qt * QBLK + wid * 32 + q31) * HDIM + hd * HD;
#pragma unroll
    for (int kc = 0; kc < 4; ++kc)
        qB[kc] = *(const bf16x8*)(qp + 16 * kc + 8 * g1);

    float m0 = 0.f;
    f32x4 l4 = (f32x4){0.f, 0.f, 0.f, 0.f};
    f32x16 accO[2];
#pragma unroll
    for (int dh = 0; dh < 2; ++dh)
#pragma unroll
        for (int i = 0; i < 16; ++i) accO[dh][i] = 0.f;

    const unsigned short* kp0 = Kg + (size_t)(b * SEQ) * HDIM + hd * HD;
    const unsigned short* vt0 = Vt + (size_t)((b * NHEAD + hd) * HD) * SEQ;

    const float QSCL = 0.125f * LOG2E;
    const float MSCL = -10000.0f * LOG2E;

    int r0 = t >> 3,           c0 = (t & 7) * 8;
    int r1 = (t + 256) >> 3,   c1 = c0;

    *(us8*)&Ks[0][r0][c0] = *(const us8*)(kp0 + (size_t)r0 * HDIM + c0);
    *(us8*)&Ks[0][r1][c1] = *(const us8*)(kp0 + (size_t)r1 * HDIM + c1);
    *(us8*)&Vs[0][r0][c0] = *(const us8*)(vt0 + (size_t)r0 * SEQ + c0);
    *(us8*)&Vs[0][r1][c1] = *(const us8*)(vt0 + (size_t)r1 * SEQ + c1);
    if (t < 64) Msd[0][t] = (1.0f - mask[b * SEQ + t]) * MSCL;
    __syncthreads();

    int cur = 0;
    for (int kt = 0; kt < NT; ++kt) {
        us8 knr0, knr1, vnr0, vnr1;
        float mreg = 1.0f;
        bool more = (kt + 1 < NT);
        if (more) {
            const unsigned short* kp = kp0 + (size_t)(kt + 1) * KVB * HDIM;
            const unsigned short* vp = vt0 + (kt + 1) * KVB;
            knr0 = *(const us8*)(kp + (size_t)r0 * HDIM + c0);
            knr1 = *(const us8*)(kp + (size_t)r1 * HDIM + c1);
            vnr0 = *(const us8*)(vp + (size_t)r0 * SEQ + c0);
            vnr1 = *(const us8*)(vp + (size_t)r1 * SEQ + c1);
            if (t < 64) mreg = mask[b * SEQ + (kt + 1) * KVB + t];
        }

        f32x16 sQ[2];
#pragma unroll
        for (int kvh = 0; kvh < 2; ++kvh) {
            f32x16 a;
#pragma unroll
            for (int i = 0; i < 16; ++i) a[i] = 0.f;
#pragma unroll
            for (int kc = 0; kc < 4; ++kc) {
                bf16x8 kA = *(const bf16x8*)&Ks[cur][32 * kvh + q31][16 * kc + 8 * g1];
                a = __builtin_amdgcn_mfma_f32_32x32x16_bf16(kA, qB[kc], a, 0, 0, 0);
            }
            sQ[kvh] = a;
        }

#pragma unroll
        for (int kvh = 0; kvh < 2; ++kvh)
#pragma unroll
            for (int hh = 0; hh < 4; ++hh) {
                fx4 msk = *(const fx4*)&Msd[cur][32 * kvh + 8 * hh + 4 * g1];
#pragma unroll
                for (int r = 0; r < 4; ++r)
                    sQ[kvh][4 * hh + r] = fmaf(sQ[kvh][4 * hh + r], QSCL, msk[r]);
            }

        if (kt == 0) {
            float mx = sQ[0][0];
#pragma unroll
            for (int kvh = 0; kvh < 2; ++kvh)
#pragma unroll
                for (int i = 0; i < 16; ++i) mx = fmaxf(mx, sQ[kvh][i]);
            mx = fmaxf(mx, __shfl_xor(mx, 32, 64));
            m0 = fmaxf(mx, -64.f);
        }

#pragma unroll
        for (int kvh = 0; kvh < 2; ++kvh)
#pragma unroll
            for (int hh = 0; hh < 4; ++hh)
#pragma unroll
                for (int r = 0; r < 4; ++r) {
                    float p = exp2f(sQ[kvh][4 * hh + r] - m0);
                    sQ[kvh][4 * hh + r] = p;
                    l4[r] += p;
                }

        unsigned int pkx[2][4], pky[2][4];
#pragma unroll
        for (int kvh = 0; kvh < 2; ++kvh)
#pragma unroll
            for (int hh = 0; hh < 4; ++hh) {
                pkx[kvh][hh] = cvt_pk_bf16(sQ[kvh][4 * hh + 0], sQ[kvh][4 * hh + 1]);
                pky[kvh][hh] = cvt_pk_bf16(sQ[kvh][4 * hh + 2], sQ[kvh][4 * hh + 3]);
            }

        bf16x8 pB[4];
#pragma unroll
        for (int kvh = 0; kvh < 2; ++kvh)
#pragma unroll
            for (int kc2 = 0; kc2 < 2; ++kc2) {
                unsigned int x0 = pkx[kvh][2 * kc2], x1 = pkx[kvh][2 * kc2 + 1];
                unsigned int y0 = pky[kvh][2 * kc2], y1 = pky[kvh][2 * kc2 + 1];
                asm("v_permlane32_swap_b32 %0, %1" : "+v"(x0), "+v"(x1));
                asm("v_permlane32_swap_b32 %0, %1" : "+v"(y0), "+v"(y1));
                u32x4 dd;
                dd[0] = x0; dd[1] = y0; dd[2] = x1; dd[3] = y1;
                pB[2 * kvh + kc2] = *(bf16x8*)&dd;
            }

#pragma unroll
        for (int dh = 0; dh < 2; ++dh) {
            f32x16 a = accO[dh];
#pragma unroll
            for (int kcp = 0; kcp < 4; ++kcp) {
                bf16x8 vA = *(const bf16x8*)&Vs[cur][32 * dh + q31][16 * kcp + 8 * g1];
                a = __builtin_amdgcn_mfma_f32_32x32x16_bf16(vA, pB[kcp], a, 0, 0, 0);
            }
            accO[dh] = a;
        }

        if (more) {
            *(us8*)&Ks[cur ^ 1][r0][c0] = knr0;
            *(us8*)&Ks[cur ^ 1][r1][c1] = knr1;
            *(us8*)&Vs[cur ^ 1][r0][c0] = vnr0;
            *(us8*)&Vs[cur ^ 1][r1][c1] = vnr1;
            if (t < 64) Msd[cur ^ 1][t] = (1.0f - mreg) * MSCL;
        }
        __syncthreads();
        cur ^= 1;
    }

    float l = (l4[0] + l4[1]) + (l4[2] + l4[3]);
    l += __shfl_xor(l, 32, 64);
    float inv = 1.0f / l;
    size_t row = (size_t)(b * SEQ + qt * QBLK + wid * 32 + q31);
#pragma unroll
    for (int dh = 0; dh < 2; ++dh)
#pragma unroll
        for (int hh = 0; hh < 4; ++hh) {
            us4 hv, lv;
#pragma unroll
            for (int r = 0; r < 4; ++r) {
                float o = accO[dh][4 * hh + r] * inv;
                unsigned short hi = f2bf(o);
                hv[r] = hi;
                lv[r] = f2bf(o - bf2f(hi));
            }
            size_t idx = row * HDIM + hd * HD + 32 * dh + 8 * hh + 4 * g1;
            *(us4*)&Ch[idx] = hv;
            *(us4*)&Cl[idx] = lv;
        }
}

// ---------------------------------------------------------------------------
extern "C" void kernel_launch(void* const* d_in, const int* in_sizes, int n_in,
                              void* d_out, int out_size, void* d_ws, size_t ws_size,
                              hipStream_t stream)
{
    const float* hs   = (const float*)d_in[0];
    const float* mask = (const float*)d_in[1];
    const float* Wq = (const float*)d_in[2];
    const float* Wk = (const float*)d_in[3];
    const float* Wv = (const float*)d_in[4];
    const float* Wo = (const float*)d_in[5];
    const float* Aq = (const float*)d_in[6];
    const float* Bq = (const float*)d_in[7];
    const float* Ak = (const float*)d_in[8];
    const float* Bk = (const float*)d_in[9];
    const float* Av = (const float*)d_in[10];
    const float* Bv = (const float*)d_in[11];
    const float* Ao = (const float*)d_in[12];
    const float* Bo = (const float*)d_in[13];
    float* out = (float*)d_out;

    char* w = (char*)d_ws;
    unsigned short* Xh = (unsigned short*)(w);                       // 8 MB (later Ch)
    unsigned short* Xl = (unsigned short*)(w + ((size_t)8 << 20));   // 8 MB (later Cl)
    unsigned short* WT = (unsigned short*)(w + ((size_t)16 << 20));  // 16 MB (8 planes)
    unsigned short* qb = (unsigned short*)(w + ((size_t)32 << 20));  // 8 MB
    unsigned short* kb = (unsigned short*)(w + ((size_t)40 << 20));  // 8 MB
    unsigned short* vb = (unsigned short*)(w + ((size_t)48 << 20));  // 8 MB
    unsigned short* vt = (unsigned short*)(w + ((size_t)56 << 20));  // 8 MB
    float* hsA  = (float*)(w + ((size_t)64 << 20));                  // 4096*24*4
    float* ctxA = (float*)(w + ((size_t)64 << 20) + 400 * 1024);     // 4096*8*4

    split_x_kernel<<<2048, 256, 0, stream>>>(hs, Xh, Xl, MTOT * HDIM / 4);
    tsplit_w_kernel<<<dim3(16, 16, 4), 256, 0, stream>>>(Wq, Wk, Wv, Wo, WT);
    lora_down_kernel<<<MTOT, 64, 0, stream>>>(hs, Aq, Ak, Av, hsA, 3);
    gemm_mfma_kernel<false, 128, 3><<<dim3(8, 96), 256, 0, stream>>>(
        Xh, WT, 0, hsA, 24, 0, Bq, Bk, Bv, qb, kb, vb);
    transpose_v_kernel<<<dim3(SEQ / 64, BATCH * NHEAD), 256, 0, stream>>>(vb, vt);
    attn_mfma_kernel<<<dim3(SEQ / QBLK, NHEAD, BATCH), 256, 0, stream>>>(
        qb, kb, vt, mask, Xh /*Ch*/, Xl /*Cl*/);
    lora_down_bf_kernel<<<MTOT, 64, 0, stream>>>(Xh, Xl, Ao, ctxA);
    gemm_mfma_kernel<true, 64, 1><<<dim3(8, 64, 1), 256, 0, stream>>>(
        Xh, WT, 3, ctxA, 8, 0, Bo, Bo, Bo, out, out, out);
}